// Round 10
// baseline (451.584 us; speedup 1.0000x reference)
//
#include <hip/hip_runtime.h>
#include <cstddef>

#define PI_F 3.14159265358979323846f
#define A_  5
#define C_  12
#define CPG 4            // coils per group
#define NG  3            // groups (CPG*NG == C_)
#define RPG (CPG * A_)   // (coil,a) rows per group = 20

// ---------------------------------------------------------------------------
// Device-global scratch, 94.4 MB (bufC eliminated by the colmix fusion).
// Per-group layouts:
//   g_bufA after k_fft1c : [ca][ym(256)][kx(512)]   (ym = padded y - 128)
//   g_bufB after k_transA: [ca][kx(512)][ym(256)]
//   g_bufA after k_colmix: [ca][kx(512)][ym(256)]   (ym = result y - 128)
//   g_bufB after k_transB: [ca][ym(256)][kx(512)]
// ca = cl*A_ + a. No atomics to d_out; max LDS 10.5 KB (proven envelope).
// ---------------------------------------------------------------------------
__device__ float2 g_bufA[RPG * 256 * 512];  // 21.0 MB
__device__ float2 g_bufB[RPG * 512 * 256];  // 21.0 MB
__device__ float2 g_kernT[25 * 512 * 512];  // 52.4 MB, transposed + pre-scaled

// ---------------------------------------------------------------------------
// Twiddle table: tab[k] = e^{-2 pi i k/512}, k in [0,256). Stage s needs
// e^{-i pi m/Ns} = tab[m << (8-s)].
// ---------------------------------------------------------------------------
__device__ inline void build_tab128(float2* tab, int t) {
    #pragma unroll
    for (int q = 0; q < 2; ++q) {
        int k = t + q * 128;
        float s, c;
        __sincosf(-2.0f * PI_F * (float)k / 512.0f, &s, &c);
        tab[k] = make_float2(c, s);
    }
}

// ---------------------------------------------------------------------------
// 512-pt Stockham radix-2 FFT in LDS, 128 threads (2 butterflies/thread).
// DIR=-1 forward (numpy sign), +1 inverse (unnormalized).
// ---------------------------------------------------------------------------
template<int DIR>
__device__ float2* fft512_tab(float2* sA, float2* sB, const float2* tab, int t) {
    float2* src = sA;
    float2* dst = sB;
    #pragma unroll
    for (int stage = 0; stage < 9; ++stage) {
        int Ns = 1 << stage;
        __syncthreads();
        #pragma unroll
        for (int q = 0; q < 2; ++q) {
            int j = t + q * 128;
            float2 v0 = src[j];
            float2 v1 = src[j + 256];
            int m = j & (Ns - 1);
            float2 w = tab[m << (8 - stage)];
            float cv = w.x;
            float sv = (DIR < 0) ? w.y : -w.y;
            float2 tw = make_float2(v1.x * cv - v1.y * sv,
                                    v1.x * sv + v1.y * cv);
            int idxD = ((j & ~(Ns - 1)) << 1) | m;
            dst[idxD]      = make_float2(v0.x + tw.x, v0.y + tw.y);
            dst[idxD + Ns] = make_float2(v0.x - tw.x, v0.y - tw.y);
        }
        float2* tmp = src; src = dst; dst = tmp;
    }
    __syncthreads();
    return src;
}

// ---------------------------------------------------------------------------
// Same FFT with 256 threads (1 butterfly/thread) for k_colmix.
// ---------------------------------------------------------------------------
template<int DIR>
__device__ float2* fft512_tab256(float2* sA, float2* sB, const float2* tab, int t) {
    float2* src = sA;
    float2* dst = sB;
    #pragma unroll
    for (int stage = 0; stage < 9; ++stage) {
        int Ns = 1 << stage;
        __syncthreads();
        int j = t;
        float2 v0 = src[j];
        float2 v1 = src[j + 256];
        int m = j & (Ns - 1);
        float2 w = tab[m << (8 - stage)];
        float cv = w.x;
        float sv = (DIR < 0) ? w.y : -w.y;
        float2 tw = make_float2(v1.x * cv - v1.y * sv,
                                v1.x * sv + v1.y * cv);
        int idxD = ((j & ~(Ns - 1)) << 1) | m;
        dst[idxD]      = make_float2(v0.x + tw.x, v0.y + tw.y);
        dst[idxD + Ns] = make_float2(v0.x - tw.x, v0.y - tw.y);
        float2* tmp = src; src = dst; dst = tmp;
    }
    __syncthreads();
    return src;
}

// ---------------------------------------------------------------------------
// Transposed, pre-scaled kernel cache:
// g_kernT[m][kx*512+ky] = scale * kern[m][ky*512+kx], m = aout*5+ain.
// ---------------------------------------------------------------------------
__global__ void k_kernT2(const float* __restrict__ kr, const float* __restrict__ ki,
                         float scale) {
    __shared__ float2 tile[32][33];
    int m = blockIdx.z;
    size_t base = (size_t)m << 18;
    int c0 = blockIdx.x * 32;
    int r0 = blockIdx.y * 32;
    int tx = threadIdx.x, ty = threadIdx.y;
    for (int i = ty; i < 32; i += 8) {
        size_t idx = base + (size_t)(c0 + i) * 512 + (r0 + tx);
        tile[i][tx] = make_float2(kr[idx] * scale, ki[idx] * scale);
    }
    __syncthreads();
    for (int i = ty; i < 32; i += 8)
        g_kernT[base + (size_t)(r0 + i) * 512 + (c0 + tx)] = tile[tx][i];
}

// ---------------------------------------------------------------------------
// Pad x + modulate mps_c*x + row FFT along x, banded store. Block = ca*256+ym.
// ---------------------------------------------------------------------------
__global__ void k_fft1c(const float* __restrict__ xr, const float* __restrict__ xi,
                        const float* __restrict__ mr, const float* __restrict__ mi,
                        int coilBase) {
    int row = blockIdx.x;            // ca*256 + ym
    int ca = row >> 8;
    int ym = row & 255;
    int cl = ca / A_;
    int a = ca - cl * A_;
    int coil = coilBase + cl;
    int t = threadIdx.x;
    __shared__ float2 sA[512], sB[512], tab[256];
    build_tab128(tab, t);
    size_t xBase = ((size_t)a * 256 + ym) * 256;
    size_t mBase = ((size_t)coil * 256 + ym) * 256;
    #pragma unroll
    for (int q = 0; q < 4; ++q) {
        int x5 = t + q * 128;
        float2 v = make_float2(0.f, 0.f);
        if (x5 >= 128 && x5 < 384) {
            int xm = x5 - 128;
            float ar = xr[xBase + xm], ai = xi[xBase + xm];
            float br = mr[mBase + xm], bi = mi[mBase + xm];
            v = make_float2(ar * br - ai * bi, ar * bi + ai * br);
        }
        sA[x5] = v;
    }
    float2* res = fft512_tab<-1>(sA, sB, tab, t);
    float2* o = g_bufA + (size_t)row * 512;
    #pragma unroll
    for (int q = 0; q < 4; ++q) o[t + q * 128] = res[t + q * 128];
}

// ---------------------------------------------------------------------------
// transA: per-ca transpose (256 ym x 512 kx) -> (512 kx x 256 ym).
// ---------------------------------------------------------------------------
__global__ void k_transA() {
    __shared__ float2 tile[32][33];
    int ca = blockIdx.z;
    const float2* sIn = g_bufA + (size_t)ca * (256 * 512);
    float2* sOut = g_bufB + (size_t)ca * (512 * 256);
    int kx0 = blockIdx.x * 32, ym0 = blockIdx.y * 32;
    int tx = threadIdx.x, ty = threadIdx.y;
    for (int i = ty; i < 32; i += 8)
        tile[i][tx] = sIn[(size_t)(ym0 + i) * 512 + kx0 + tx];
    __syncthreads();
    for (int i = ty; i < 32; i += 8)
        sOut[(size_t)(kx0 + i) * 256 + ym0 + tx] = tile[tx][i];
}

// ---------------------------------------------------------------------------
// FUSED column pipeline, block = (kx, cl), 256 threads, 10.5 KB LDS:
//   for ain in 0..4: banded load + pad -> fwd FFT (LDS) -> spectrum to REGS
//   25-term register mix with pre-scaled kernT (coalesced reads)
//   for aout in 0..4: inv FFT (LDS) -> banded store to g_bufA[ca][kx][ym]
// Eliminates the bufC round trip and the 5x bufC re-read across aout that
// made R9's k_mixifft memory-bound (FETCH 141.7 MB/dispatch).
// Race note: each thread's reads of res (=sB) precede its sA refill and the
// next FFT's entry __syncthreads in program order, so stage-0 writes to sB
// cannot overtake them.
// ---------------------------------------------------------------------------
__global__ void __launch_bounds__(256) k_colmix() {
    int kx = blockIdx.x;
    int cl = blockIdx.y;
    int t = threadIdx.x;             // 0..255
    __shared__ float2 sA[512], sB[512], tab[256];
    {
        float s, c;
        __sincosf(-2.0f * PI_F * (float)t / 512.0f, &s, &c);
        tab[t] = make_float2(c, s);
    }
    float2 F[A_][2];
    for (int r = 0; r < A_; ++r) {
        const float2* grow = g_bufB + ((size_t)((cl * A_ + r) * 512 + kx)) * 256;
        sA[t]       = (t >= 128) ? grow[t - 128] : make_float2(0.f, 0.f);
        sA[t + 256] = (t < 128)  ? grow[t + 128] : make_float2(0.f, 0.f);
        float2* res = fft512_tab256<-1>(sA, sB, tab, t);
        F[r][0] = res[t];
        F[r][1] = res[t + 256];
    }
    float2 acc[A_][2];
    size_t kxb = (size_t)kx << 9;
    #pragma unroll
    for (int aout = 0; aout < A_; ++aout) {
        acc[aout][0] = make_float2(0.f, 0.f);
        acc[aout][1] = make_float2(0.f, 0.f);
        #pragma unroll
        for (int ain = 0; ain < A_; ++ain) {
            size_t mb = ((size_t)(aout * A_ + ain) << 18) + kxb;
            float2 k0 = g_kernT[mb + t];
            float2 k1 = g_kernT[mb + t + 256];
            acc[aout][0].x += k0.x * F[ain][0].x - k0.y * F[ain][0].y;
            acc[aout][0].y += k0.x * F[ain][0].y + k0.y * F[ain][0].x;
            acc[aout][1].x += k1.x * F[ain][1].x - k1.y * F[ain][1].y;
            acc[aout][1].y += k1.x * F[ain][1].y + k1.y * F[ain][1].x;
        }
    }
    for (int aout = 0; aout < A_; ++aout) {
        sA[t]       = acc[aout][0];
        sA[t + 256] = acc[aout][1];
        float2* res = fft512_tab256<1>(sA, sB, tab, t);
        // keep y in [128,384): ym = t
        g_bufA[((size_t)((cl * A_ + aout) * 512 + kx)) * 256 + t] = res[t + 128];
    }
}

// ---------------------------------------------------------------------------
// transB: per-ca transpose (512 kx x 256 ym) -> (256 ym x 512 kx).
// ---------------------------------------------------------------------------
__global__ void k_transB() {
    __shared__ float2 tile[32][33];
    int ca = blockIdx.z;
    const float2* sIn = g_bufA + (size_t)ca * (512 * 256);
    float2* sOut = g_bufB + (size_t)ca * (256 * 512);
    int ym0 = blockIdx.x * 32, kx0 = blockIdx.y * 32;
    int tx = threadIdx.x, ty = threadIdx.y;
    for (int i = ty; i < 32; i += 8)
        tile[i][tx] = sIn[(size_t)(kx0 + i) * 256 + ym0 + tx];
    __syncthreads();
    for (int i = ty; i < 32; i += 8)
        sOut[(size_t)(ym0 + i) * 512 + kx0 + tx] = tile[tx][i];
}

// ---------------------------------------------------------------------------
// Final stage: block (a,h) owns all CPG coils of the group — CPG sequential
// row IFFTs, conj(mps)*v accumulated in registers, one plain write/+= per
// element. Planar out: Re plane [5,256,256] then Im plane. No atomics.
// ---------------------------------------------------------------------------
__global__ void k_out_g(const float* __restrict__ mr, const float* __restrict__ mi,
                        int coilBase, int first, float* __restrict__ out,
                        int outFloats) {
    int row = blockIdx.x;            // a*256 + h
    int a = row >> 8;
    int h = row & 255;
    int t = threadIdx.x;
    __shared__ float2 sA[512], sB[512], tab[256];
    build_tab128(tab, t);
    float accr[2] = {0.f, 0.f}, acci[2] = {0.f, 0.f};
    for (int cl = 0; cl < CPG; ++cl) {
        const float2* s = g_bufB + (((size_t)(cl * A_ + a) * 256 + h)) * 512;
        #pragma unroll
        for (int q = 0; q < 4; ++q) sA[t + q * 128] = s[t + q * 128];
        float2* res = fft512_tab<1>(sA, sB, tab, t);
        int coil = coilBase + cl;
        #pragma unroll
        for (int q = 0; q < 2; ++q) {
            int w = t + q * 128;
            float2 v = res[w + 128];
            size_t mIdx = ((size_t)coil * 256 + h) * 256 + w;
            float br = mr[mIdx], bi = -mi[mIdx];   // conj(mps)
            accr[q] += v.x * br - v.y * bi;
            acci[q] += v.x * bi + v.y * br;
        }
        __syncthreads();
    }
    #pragma unroll
    for (int q = 0; q < 2; ++q) {
        int w = t + q * 128;
        size_t p = ((size_t)a * 256 + h) * 256 + w;
        size_t reIdx = p, imIdx = 327680 + p;
        if (first) {
            if (reIdx < (size_t)outFloats) out[reIdx] = accr[q];
            if (imIdx < (size_t)outFloats) out[imIdx] = acci[q];
        } else {
            if (reIdx < (size_t)outFloats) out[reIdx] += accr[q];
            if (imIdx < (size_t)outFloats) out[imIdx] += acci[q];
        }
    }
}

// ---------------------------------------------------------------------------
extern "C" void kernel_launch(void* const* d_in, const int* in_sizes, int n_in,
                              void* d_out, int out_size, void* d_ws, size_t ws_size,
                              hipStream_t stream) {
    const float* xr = (const float*)d_in[0];
    const float* xi = (const float*)d_in[1];
    const float* mr = (const float*)d_in[2];
    const float* mi = (const float*)d_in[3];
    const float* kr = (const float*)d_in[4];
    const float* ki = (const float*)d_in[5];
    float* out = (float*)d_out;
    (void)d_ws; (void)ws_size; (void)n_in; (void)in_sizes;

    const float scale = 4.0f / 262144.0f;   // OVERSAMP^2/(Hp*Wp), ortho norms

    k_kernT2<<<dim3(16, 16, 25), dim3(32, 8), 0, stream>>>(kr, ki, scale);

    for (int g = 0; g < NG; ++g) {
        int cb = g * CPG;
        k_fft1c<<<RPG * 256, 128, 0, stream>>>(xr, xi, mr, mi, cb);
        k_transA<<<dim3(16, 8, RPG), dim3(32, 8), 0, stream>>>();
        k_colmix<<<dim3(512, CPG), 256, 0, stream>>>();
        k_transB<<<dim3(8, 16, RPG), dim3(32, 8), 0, stream>>>();
        k_out_g<<<A_ * 256, 128, 0, stream>>>(mr, mi, cb, (g == 0) ? 1 : 0,
                                              out, out_size);
    }
}

// Round 11
// 443.516 us; speedup vs baseline: 1.0182x; 1.0182x over previous
//
#include <hip/hip_runtime.h>
#include <cstddef>

#define PI_F 3.14159265358979323846f
#define A_  5
#define C_  12
#define CPG 12           // all coils in one pass
#define RPG (CPG * A_)   // (coil,a) rows = 60

// ---------------------------------------------------------------------------
// Device-global scratch, 304 MB. No atomics / no >10.5KB-LDS kernel (the two
// R6/R7 crash suspects). R7 reproduced the abort at 73 MB, so BSS size is
// not implicated; this round also serves as the controlled BSS experiment.
// Layouts:
//   g_bufA after k_fft1c  : [ca][ym(256)][kx(512)]  (ym = padded y - 128)
//   g_bufB after k_transA : [ca][kx(512)][ym(256)]
//   g_bufC after k_colfft : [ca][kx(512)][ky(512)]
//   g_bufA after k_mixifft: [ca][kx(512)][ym(256)]  (ym = result y - 128)
//   g_bufB after k_transB : [ca][ym(256)][kx(512)]
//   g_bufA after k_outifft: [ca][h(256)][w(256)]    (cropped image rows)
// ca = cl*A_ + a.
// ---------------------------------------------------------------------------
__device__ float2 g_bufA[RPG * 256 * 512];  //  63 MB
__device__ float2 g_bufB[RPG * 512 * 256];  //  63 MB
__device__ float2 g_bufC[RPG * 512 * 512];  // 126 MB
__device__ float2 g_kernT[25 * 512 * 512];  // 52.4 MB, transposed + pre-scaled

// ---------------------------------------------------------------------------
// Twiddle table: tab[k] = e^{-2 pi i k/512}, k in [0,256). Stage s needs
// e^{-i pi m/Ns} = tab[m << (8-s)].
// ---------------------------------------------------------------------------
__device__ inline void build_tab128(float2* tab, int t) {
    #pragma unroll
    for (int q = 0; q < 2; ++q) {
        int k = t + q * 128;
        float s, c;
        __sincosf(-2.0f * PI_F * (float)k / 512.0f, &s, &c);
        tab[k] = make_float2(c, s);
    }
}

// ---------------------------------------------------------------------------
// 512-pt Stockham radix-2 FFT in LDS, 128 threads, table twiddles.
// DIR=-1 forward (numpy sign), +1 inverse (unnormalized).
// ---------------------------------------------------------------------------
template<int DIR>
__device__ float2* fft512_tab(float2* sA, float2* sB, const float2* tab, int t) {
    float2* src = sA;
    float2* dst = sB;
    #pragma unroll
    for (int stage = 0; stage < 9; ++stage) {
        int Ns = 1 << stage;
        __syncthreads();
        #pragma unroll
        for (int q = 0; q < 2; ++q) {
            int j = t + q * 128;
            float2 v0 = src[j];
            float2 v1 = src[j + 256];
            int m = j & (Ns - 1);
            float2 w = tab[m << (8 - stage)];
            float cv = w.x;
            float sv = (DIR < 0) ? w.y : -w.y;
            float2 tw = make_float2(v1.x * cv - v1.y * sv,
                                    v1.x * sv + v1.y * cv);
            int idxD = ((j & ~(Ns - 1)) << 1) | m;
            dst[idxD]      = make_float2(v0.x + tw.x, v0.y + tw.y);
            dst[idxD + Ns] = make_float2(v0.x - tw.x, v0.y - tw.y);
        }
        float2* tmp = src; src = dst; dst = tmp;
    }
    __syncthreads();
    return src;
}

// ---------------------------------------------------------------------------
// Transposed, pre-scaled kernel cache:
// g_kernT[m][kx*512+ky] = scale * kern[m][ky*512+kx], m = aout*5+ain.
// ---------------------------------------------------------------------------
__global__ void k_kernT2(const float* __restrict__ kr, const float* __restrict__ ki,
                         float scale) {
    __shared__ float2 tile[32][33];
    int m = blockIdx.z;
    size_t base = (size_t)m << 18;
    int c0 = blockIdx.x * 32;
    int r0 = blockIdx.y * 32;
    int tx = threadIdx.x, ty = threadIdx.y;
    for (int i = ty; i < 32; i += 8) {
        size_t idx = base + (size_t)(c0 + i) * 512 + (r0 + tx);
        tile[i][tx] = make_float2(kr[idx] * scale, ki[idx] * scale);
    }
    __syncthreads();
    for (int i = ty; i < 32; i += 8)
        g_kernT[base + (size_t)(r0 + i) * 512 + (c0 + tx)] = tile[tx][i];
}

// ---------------------------------------------------------------------------
// Pad x + modulate mps_c*x + row FFT along x, banded store. Block = ca*256+ym.
// ---------------------------------------------------------------------------
__global__ void k_fft1c(const float* __restrict__ xr, const float* __restrict__ xi,
                        const float* __restrict__ mr, const float* __restrict__ mi) {
    int row = blockIdx.x;            // ca*256 + ym
    int ca = row >> 8;
    int ym = row & 255;
    int coil = ca / A_;
    int a = ca - coil * A_;
    int t = threadIdx.x;
    __shared__ float2 sA[512], sB[512], tab[256];
    build_tab128(tab, t);
    size_t xBase = ((size_t)a * 256 + ym) * 256;
    size_t mBase = ((size_t)coil * 256 + ym) * 256;
    #pragma unroll
    for (int q = 0; q < 4; ++q) {
        int x5 = t + q * 128;
        float2 v = make_float2(0.f, 0.f);
        if (x5 >= 128 && x5 < 384) {
            int xm = x5 - 128;
            float ar = xr[xBase + xm], ai = xi[xBase + xm];
            float br = mr[mBase + xm], bi = mi[mBase + xm];
            v = make_float2(ar * br - ai * bi, ar * bi + ai * br);
        }
        sA[x5] = v;
    }
    float2* res = fft512_tab<-1>(sA, sB, tab, t);
    float2* o = g_bufA + (size_t)row * 512;
    #pragma unroll
    for (int q = 0; q < 4; ++q) o[t + q * 128] = res[t + q * 128];
}

// ---------------------------------------------------------------------------
// transA: per-ca transpose (256 ym x 512 kx) -> (512 kx x 256 ym).
// ---------------------------------------------------------------------------
__global__ void k_transA() {
    __shared__ float2 tile[32][33];
    int ca = blockIdx.z;
    const float2* sIn = g_bufA + (size_t)ca * (256 * 512);
    float2* sOut = g_bufB + (size_t)ca * (512 * 256);
    int kx0 = blockIdx.x * 32, ym0 = blockIdx.y * 32;
    int tx = threadIdx.x, ty = threadIdx.y;
    for (int i = ty; i < 32; i += 8)
        tile[i][tx] = sIn[(size_t)(ym0 + i) * 512 + kx0 + tx];
    __syncthreads();
    for (int i = ty; i < 32; i += 8)
        sOut[(size_t)(kx0 + i) * 256 + ym0 + tx] = tile[tx][i];
}

// ---------------------------------------------------------------------------
// Column FFT with pad-on-load: block = ca*512 + kx; read 256 band, pad to
// 512, forward FFT, write full ky row into bufC.
// ---------------------------------------------------------------------------
__global__ void k_colfft() {
    int blk = blockIdx.x;            // ca*512 + kx
    int t = threadIdx.x;
    __shared__ float2 sA[512], sB[512], tab[256];
    build_tab128(tab, t);
    const float2* grow = g_bufB + (size_t)blk * 256;
    #pragma unroll
    for (int q = 0; q < 4; ++q) {
        int y = t + q * 128;
        sA[y] = (y >= 128 && y < 384) ? grow[y - 128] : make_float2(0.f, 0.f);
    }
    float2* res = fft512_tab<-1>(sA, sB, tab, t);
    float2* o = g_bufC + (size_t)blk * 512;
    #pragma unroll
    for (int q = 0; q < 4; ++q) o[t + q * 128] = res[t + q * 128];
}

// ---------------------------------------------------------------------------
// K-space mix + column IFFT, banded store. KX-MAJOR block order: the 60
// blocks sharing one kx cluster in dispatch order, so they reuse the same
// 25 kernT rows (102 KB) and 60 bufC rows in L2/L3 across aout AND cl —
// R9's ca-major order re-fetched bufC 5x and kernT per group.
// ---------------------------------------------------------------------------
__global__ void k_mixifft() {
    int blk = blockIdx.x;            // kx*RPG + ca
    int kx = blk / RPG;
    int ca = blk - kx * RPG;
    int cl = ca / A_;
    int aout = ca - cl * A_;
    int t = threadIdx.x;
    __shared__ float2 sA[512], sB[512], tab[256];
    build_tab128(tab, t);
    #pragma unroll
    for (int q = 0; q < 4; ++q) {
        int ky = t + q * 128;
        float2 acc = make_float2(0.f, 0.f);
        #pragma unroll
        for (int ain = 0; ain < A_; ++ain) {
            float2 kv = g_kernT[(((size_t)(aout * A_ + ain)) << 18) +
                                ((size_t)kx << 9) + ky];
            float2 fv = g_bufC[(((size_t)(cl * A_ + ain)) << 18) +
                               ((size_t)kx << 9) + ky];
            acc.x += kv.x * fv.x - kv.y * fv.y;
            acc.y += kv.x * fv.y + kv.y * fv.x;
        }
        sA[ky] = acc;
    }
    float2* res = fft512_tab<1>(sA, sB, tab, t);
    // keep y in [128,384) -> ym = y-128; store [ca][kx][ym]
    float2* o = g_bufA + ((size_t)ca * 512 + kx) * 256;
    o[t]       = res[t + 128];
    o[t + 128] = res[t + 256];
}

// ---------------------------------------------------------------------------
// transB: per-ca transpose (512 kx x 256 ym) -> (256 ym x 512 kx).
// ---------------------------------------------------------------------------
__global__ void k_transB() {
    __shared__ float2 tile[32][33];
    int ca = blockIdx.z;
    const float2* sIn = g_bufA + (size_t)ca * (512 * 256);
    float2* sOut = g_bufB + (size_t)ca * (256 * 512);
    int ym0 = blockIdx.x * 32, kx0 = blockIdx.y * 32;
    int tx = threadIdx.x, ty = threadIdx.y;
    for (int i = ty; i < 32; i += 8)
        tile[i][tx] = sIn[(size_t)(kx0 + i) * 256 + ym0 + tx];
    __syncthreads();
    for (int i = ty; i < 32; i += 8)
        sOut[(size_t)(ym0 + i) * 512 + kx0 + tx] = tile[tx][i];
}

// ---------------------------------------------------------------------------
// Row IFFT along kx + crop x, banded store [ca][h][w(256)]. Fully parallel
// (replaces R9's serial per-block coil loop in k_out_g).
// ---------------------------------------------------------------------------
__global__ void k_outifft() {
    int row = blockIdx.x;            // ca*256 + h
    int t = threadIdx.x;
    __shared__ float2 sA[512], sB[512], tab[256];
    build_tab128(tab, t);
    const float2* s = g_bufB + (size_t)row * 512;
    #pragma unroll
    for (int q = 0; q < 4; ++q) sA[t + q * 128] = s[t + q * 128];
    float2* res = fft512_tab<1>(sA, sB, tab, t);
    float2* o = g_bufA + (size_t)row * 256;
    #pragma unroll
    for (int q = 0; q < 2; ++q) {
        int w = t + q * 128;
        o[w] = res[w + 128];         // crop x: keep [128,384)
    }
}

// ---------------------------------------------------------------------------
// Coil reduction: out[a,h,w] = sum_c conj(mps[c,h,w]) * v[c,a,h,w].
// One plain write per element (covers the poisoned buffer; no memset, no
// atomics, no first-flag). Planar out: Re plane [5,256,256] then Im plane.
// ---------------------------------------------------------------------------
__global__ void k_outred(const float* __restrict__ mr, const float* __restrict__ mi,
                         float* __restrict__ out, int outFloats) {
    int row = blockIdx.x;            // a*256 + h
    int a = row >> 8;
    int h = row & 255;
    int w = threadIdx.x;             // 0..255
    float ar = 0.f, ai = 0.f;
    #pragma unroll
    for (int c = 0; c < C_; ++c) {
        float2 v = g_bufA[(((size_t)(c * A_ + a) * 256 + h)) * 256 + w];
        size_t mIdx = ((size_t)c * 256 + h) * 256 + w;
        float br = mr[mIdx], bi = -mi[mIdx];   // conj(mps)
        ar += v.x * br - v.y * bi;
        ai += v.x * bi + v.y * br;
    }
    size_t p = ((size_t)a * 256 + h) * 256 + w;
    size_t reIdx = p, imIdx = 327680 + p;
    if (reIdx < (size_t)outFloats) out[reIdx] = ar;
    if (imIdx < (size_t)outFloats) out[imIdx] = ai;
}

// ---------------------------------------------------------------------------
extern "C" void kernel_launch(void* const* d_in, const int* in_sizes, int n_in,
                              void* d_out, int out_size, void* d_ws, size_t ws_size,
                              hipStream_t stream) {
    const float* xr = (const float*)d_in[0];
    const float* xi = (const float*)d_in[1];
    const float* mr = (const float*)d_in[2];
    const float* mi = (const float*)d_in[3];
    const float* kr = (const float*)d_in[4];
    const float* ki = (const float*)d_in[5];
    float* out = (float*)d_out;
    (void)d_ws; (void)ws_size; (void)n_in; (void)in_sizes;

    const float scale = 4.0f / 262144.0f;   // OVERSAMP^2/(Hp*Wp), ortho norms

    k_kernT2 <<<dim3(16, 16, 25), dim3(32, 8), 0, stream>>>(kr, ki, scale);
    k_fft1c  <<<RPG * 256, 128, 0, stream>>>(xr, xi, mr, mi);
    k_transA <<<dim3(16, 8, RPG), dim3(32, 8), 0, stream>>>();
    k_colfft <<<RPG * 512, 128, 0, stream>>>();
    k_mixifft<<<RPG * 512, 128, 0, stream>>>();
    k_transB <<<dim3(8, 16, RPG), dim3(32, 8), 0, stream>>>();
    k_outifft<<<RPG * 256, 128, 0, stream>>>();
    k_outred <<<A_ * 256, 256, 0, stream>>>(mr, mi, out, out_size);
}

// Round 12
// 410.794 us; speedup vs baseline: 1.0993x; 1.0797x over previous
//
#include <hip/hip_runtime.h>
#include <cstddef>

#define PI_F 3.14159265358979323846f
#define A_  5
#define C_  12
#define CPG 12           // all coils in one pass
#define RPG (CPG * A_)   // (coil,a) rows = 60

// ---------------------------------------------------------------------------
// Device-global scratch, 304 MB (proven loadable in R11). Layouts:
//   g_bufA after k_fft1c  : [ca][ym(256)][kx(512)]  (ym = padded y - 128)
//   g_bufB after k_transA : [ca][kx(512)][ym(256)]
//   g_bufC after k_colfft : [ca][kx(512)][ky(512)]  (F spectra)
//   g_bufC after k_mix    : same slots, G = sum_ain K*F (in-place, pointwise)
//   g_bufA after k_colifft: [ca][kx(512)][ym(256)]  (ym = result y - 128)
//   g_bufB after k_transB : [ca][ym(256)][kx(512)]
//   g_bufA after k_outifft: [ca][h(256)][w(256)]
// ca = coil*A_ + a.
// ---------------------------------------------------------------------------
__device__ float2 g_bufA[RPG * 256 * 512];  //  63 MB
__device__ float2 g_bufB[RPG * 512 * 256];  //  63 MB
__device__ float2 g_bufC[RPG * 512 * 512];  // 126 MB
__device__ float2 g_kernT[25 * 512 * 512];  // 52.4 MB, transposed + pre-scaled

// ---------------------------------------------------------------------------
// Twiddle table: tab[k] = e^{-2 pi i k/512}, k in [0,256). Stage s needs
// e^{-i pi m/Ns} = tab[m << (8-s)].
// ---------------------------------------------------------------------------
__device__ inline void build_tab128(float2* tab, int t) {
    #pragma unroll
    for (int q = 0; q < 2; ++q) {
        int k = t + q * 128;
        float s, c;
        __sincosf(-2.0f * PI_F * (float)k / 512.0f, &s, &c);
        tab[k] = make_float2(c, s);
    }
}

// ---------------------------------------------------------------------------
// 512-pt Stockham radix-2 FFT in LDS, 128 threads, table twiddles.
// DIR=-1 forward (numpy sign), +1 inverse (unnormalized).
// ---------------------------------------------------------------------------
template<int DIR>
__device__ float2* fft512_tab(float2* sA, float2* sB, const float2* tab, int t) {
    float2* src = sA;
    float2* dst = sB;
    #pragma unroll
    for (int stage = 0; stage < 9; ++stage) {
        int Ns = 1 << stage;
        __syncthreads();
        #pragma unroll
        for (int q = 0; q < 2; ++q) {
            int j = t + q * 128;
            float2 v0 = src[j];
            float2 v1 = src[j + 256];
            int m = j & (Ns - 1);
            float2 w = tab[m << (8 - stage)];
            float cv = w.x;
            float sv = (DIR < 0) ? w.y : -w.y;
            float2 tw = make_float2(v1.x * cv - v1.y * sv,
                                    v1.x * sv + v1.y * cv);
            int idxD = ((j & ~(Ns - 1)) << 1) | m;
            dst[idxD]      = make_float2(v0.x + tw.x, v0.y + tw.y);
            dst[idxD + Ns] = make_float2(v0.x - tw.x, v0.y - tw.y);
        }
        float2* tmp = src; src = dst; dst = tmp;
    }
    __syncthreads();
    return src;
}

// ---------------------------------------------------------------------------
// Transposed, pre-scaled kernel cache:
// g_kernT[m][kx*512+ky] = scale * kern[m][ky*512+kx], m = aout*5+ain.
// ---------------------------------------------------------------------------
__global__ void k_kernT2(const float* __restrict__ kr, const float* __restrict__ ki,
                         float scale) {
    __shared__ float2 tile[32][33];
    int m = blockIdx.z;
    size_t base = (size_t)m << 18;
    int c0 = blockIdx.x * 32;
    int r0 = blockIdx.y * 32;
    int tx = threadIdx.x, ty = threadIdx.y;
    for (int i = ty; i < 32; i += 8) {
        size_t idx = base + (size_t)(c0 + i) * 512 + (r0 + tx);
        tile[i][tx] = make_float2(kr[idx] * scale, ki[idx] * scale);
    }
    __syncthreads();
    for (int i = ty; i < 32; i += 8)
        g_kernT[base + (size_t)(r0 + i) * 512 + (c0 + tx)] = tile[tx][i];
}

// ---------------------------------------------------------------------------
// Pad x + modulate mps_c*x + row FFT along x, banded store. Block = ca*256+ym.
// ---------------------------------------------------------------------------
__global__ void k_fft1c(const float* __restrict__ xr, const float* __restrict__ xi,
                        const float* __restrict__ mr, const float* __restrict__ mi) {
    int row = blockIdx.x;            // ca*256 + ym
    int ca = row >> 8;
    int ym = row & 255;
    int coil = ca / A_;
    int a = ca - coil * A_;
    int t = threadIdx.x;
    __shared__ float2 sA[512], sB[512], tab[256];
    build_tab128(tab, t);
    size_t xBase = ((size_t)a * 256 + ym) * 256;
    size_t mBase = ((size_t)coil * 256 + ym) * 256;
    #pragma unroll
    for (int q = 0; q < 4; ++q) {
        int x5 = t + q * 128;
        float2 v = make_float2(0.f, 0.f);
        if (x5 >= 128 && x5 < 384) {
            int xm = x5 - 128;
            float ar = xr[xBase + xm], ai = xi[xBase + xm];
            float br = mr[mBase + xm], bi = mi[mBase + xm];
            v = make_float2(ar * br - ai * bi, ar * bi + ai * br);
        }
        sA[x5] = v;
    }
    float2* res = fft512_tab<-1>(sA, sB, tab, t);
    float2* o = g_bufA + (size_t)row * 512;
    #pragma unroll
    for (int q = 0; q < 4; ++q) o[t + q * 128] = res[t + q * 128];
}

// ---------------------------------------------------------------------------
// transA: per-ca transpose (256 ym x 512 kx) -> (512 kx x 256 ym).
// ---------------------------------------------------------------------------
__global__ void k_transA() {
    __shared__ float2 tile[32][33];
    int ca = blockIdx.z;
    const float2* sIn = g_bufA + (size_t)ca * (256 * 512);
    float2* sOut = g_bufB + (size_t)ca * (512 * 256);
    int kx0 = blockIdx.x * 32, ym0 = blockIdx.y * 32;
    int tx = threadIdx.x, ty = threadIdx.y;
    for (int i = ty; i < 32; i += 8)
        tile[i][tx] = sIn[(size_t)(ym0 + i) * 512 + kx0 + tx];
    __syncthreads();
    for (int i = ty; i < 32; i += 8)
        sOut[(size_t)(kx0 + i) * 256 + ym0 + tx] = tile[tx][i];
}

// ---------------------------------------------------------------------------
// Column FFT with pad-on-load: block = ca*512 + kx; read 256 band, pad to
// 512, forward FFT, write full ky row into bufC.
// ---------------------------------------------------------------------------
__global__ void k_colfft() {
    int blk = blockIdx.x;            // ca*512 + kx
    int t = threadIdx.x;
    __shared__ float2 sA[512], sB[512], tab[256];
    build_tab128(tab, t);
    const float2* grow = g_bufB + (size_t)blk * 256;
    #pragma unroll
    for (int q = 0; q < 4; ++q) {
        int y = t + q * 128;
        sA[y] = (y >= 128 && y < 384) ? grow[y - 128] : make_float2(0.f, 0.f);
    }
    float2* res = fft512_tab<-1>(sA, sB, tab, t);
    float2* o = g_bufC + (size_t)blk * 512;
    #pragma unroll
    for (int q = 0; q < 4; ++q) o[t + q * 128] = res[t + q * 128];
}

// ---------------------------------------------------------------------------
// Pointwise k-space mix, IN PLACE over bufC, minimal-traffic streaming:
// each thread owns one (kx,ky), holds the 25 kernT values in REGISTERS, and
// loops all 12 coils: load 5 F, compute 5 G, store 5 G over the same slots.
// kernT read once (52.4 MB), bufC read+written once (126+126 MB) — vs R11's
// fused kernel whose demand was 5x bufC + 12x kernT (FETCH 532 MB measured).
// In-place safety: G[aout](kx,ky) depends only on F[ain](kx,ky) of the SAME
// k-point, held in registers before any store. No LDS, no syncs.
// ---------------------------------------------------------------------------
__global__ void __launch_bounds__(256) k_mix() {
    int blk = blockIdx.x;                    // kx*2 + half
    int kx = blk >> 1;
    int ky = ((blk & 1) << 8) + threadIdx.x; // 0..511
    size_t off = ((size_t)kx << 9) + ky;
    float2 K[25];
    #pragma unroll
    for (int m = 0; m < 25; ++m)
        K[m] = g_kernT[((size_t)m << 18) + off];
    for (int cl = 0; cl < C_; ++cl) {
        float2 F[A_], G[A_];
        #pragma unroll
        for (int ain = 0; ain < A_; ++ain)
            F[ain] = g_bufC[((size_t)(cl * A_ + ain) << 18) + off];
        #pragma unroll
        for (int aout = 0; aout < A_; ++aout) {
            float2 acc = make_float2(0.f, 0.f);
            #pragma unroll
            for (int ain = 0; ain < A_; ++ain) {
                float2 k = K[aout * A_ + ain];
                acc.x += k.x * F[ain].x - k.y * F[ain].y;
                acc.y += k.x * F[ain].y + k.y * F[ain].x;
            }
            G[aout] = acc;
        }
        #pragma unroll
        for (int aout = 0; aout < A_; ++aout)
            g_bufC[((size_t)(cl * A_ + aout) << 18) + off] = G[aout];
    }
}

// ---------------------------------------------------------------------------
// Column IFFT over ky, banded store of the surviving center band.
// Block = ca*512 + kx (R9-proven body, mix removed).
// ---------------------------------------------------------------------------
__global__ void k_colifft() {
    int blk = blockIdx.x;            // ca*512 + kx
    int t = threadIdx.x;
    __shared__ float2 sA[512], sB[512], tab[256];
    build_tab128(tab, t);
    const float2* g = g_bufC + (size_t)blk * 512;
    #pragma unroll
    for (int q = 0; q < 4; ++q) sA[t + q * 128] = g[t + q * 128];
    float2* res = fft512_tab<1>(sA, sB, tab, t);
    // keep y in [128,384) -> ym = y-128; store [ca][kx][ym]
    float2* o = g_bufA + (size_t)blk * 256;
    o[t]       = res[t + 128];
    o[t + 128] = res[t + 256];
}

// ---------------------------------------------------------------------------
// transB: per-ca transpose (512 kx x 256 ym) -> (256 ym x 512 kx).
// ---------------------------------------------------------------------------
__global__ void k_transB() {
    __shared__ float2 tile[32][33];
    int ca = blockIdx.z;
    const float2* sIn = g_bufA + (size_t)ca * (512 * 256);
    float2* sOut = g_bufB + (size_t)ca * (256 * 512);
    int ym0 = blockIdx.x * 32, kx0 = blockIdx.y * 32;
    int tx = threadIdx.x, ty = threadIdx.y;
    for (int i = ty; i < 32; i += 8)
        tile[i][tx] = sIn[(size_t)(kx0 + i) * 256 + ym0 + tx];
    __syncthreads();
    for (int i = ty; i < 32; i += 8)
        sOut[(size_t)(ym0 + i) * 512 + kx0 + tx] = tile[tx][i];
}

// ---------------------------------------------------------------------------
// Row IFFT along kx + crop x, banded store [ca][h][w(256)].
// ---------------------------------------------------------------------------
__global__ void k_outifft() {
    int row = blockIdx.x;            // ca*256 + h
    int t = threadIdx.x;
    __shared__ float2 sA[512], sB[512], tab[256];
    build_tab128(tab, t);
    const float2* s = g_bufB + (size_t)row * 512;
    #pragma unroll
    for (int q = 0; q < 4; ++q) sA[t + q * 128] = s[t + q * 128];
    float2* res = fft512_tab<1>(sA, sB, tab, t);
    float2* o = g_bufA + (size_t)row * 256;
    #pragma unroll
    for (int q = 0; q < 2; ++q) {
        int w = t + q * 128;
        o[w] = res[w + 128];         // crop x: keep [128,384)
    }
}

// ---------------------------------------------------------------------------
// Coil reduction: out[a,h,w] = sum_c conj(mps[c,h,w]) * v[c,a,h,w].
// One plain write per element. Planar out: Re plane [5,256,256] then Im.
// ---------------------------------------------------------------------------
__global__ void k_outred(const float* __restrict__ mr, const float* __restrict__ mi,
                         float* __restrict__ out, int outFloats) {
    int row = blockIdx.x;            // a*256 + h
    int a = row >> 8;
    int h = row & 255;
    int w = threadIdx.x;             // 0..255
    float ar = 0.f, ai = 0.f;
    #pragma unroll
    for (int c = 0; c < C_; ++c) {
        float2 v = g_bufA[(((size_t)(c * A_ + a) * 256 + h)) * 256 + w];
        size_t mIdx = ((size_t)c * 256 + h) * 256 + w;
        float br = mr[mIdx], bi = -mi[mIdx];   // conj(mps)
        ar += v.x * br - v.y * bi;
        ai += v.x * bi + v.y * br;
    }
    size_t p = ((size_t)a * 256 + h) * 256 + w;
    size_t reIdx = p, imIdx = 327680 + p;
    if (reIdx < (size_t)outFloats) out[reIdx] = ar;
    if (imIdx < (size_t)outFloats) out[imIdx] = ai;
}

// ---------------------------------------------------------------------------
extern "C" void kernel_launch(void* const* d_in, const int* in_sizes, int n_in,
                              void* d_out, int out_size, void* d_ws, size_t ws_size,
                              hipStream_t stream) {
    const float* xr = (const float*)d_in[0];
    const float* xi = (const float*)d_in[1];
    const float* mr = (const float*)d_in[2];
    const float* mi = (const float*)d_in[3];
    const float* kr = (const float*)d_in[4];
    const float* ki = (const float*)d_in[5];
    float* out = (float*)d_out;
    (void)d_ws; (void)ws_size; (void)n_in; (void)in_sizes;

    const float scale = 4.0f / 262144.0f;   // OVERSAMP^2/(Hp*Wp), ortho norms

    k_kernT2 <<<dim3(16, 16, 25), dim3(32, 8), 0, stream>>>(kr, ki, scale);
    k_fft1c  <<<RPG * 256, 128, 0, stream>>>(xr, xi, mr, mi);
    k_transA <<<dim3(16, 8, RPG), dim3(32, 8), 0, stream>>>();
    k_colfft <<<RPG * 512, 128, 0, stream>>>();
    k_mix    <<<1024, 256, 0, stream>>>();
    k_colifft<<<RPG * 512, 128, 0, stream>>>();
    k_transB <<<dim3(8, 16, RPG), dim3(32, 8), 0, stream>>>();
    k_outifft<<<RPG * 256, 128, 0, stream>>>();
    k_outred <<<A_ * 256, 256, 0, stream>>>(mr, mi, out, out_size);
}

// Round 13
// 389.588 us; speedup vs baseline: 1.1591x; 1.0544x over previous
//
#include <hip/hip_runtime.h>
#include <cstddef>

#define PI_F 3.14159265358979323846f
#define A_  5
#define C_  12
#define RPG (C_ * A_)    // (coil,a) rows = 60

// ---------------------------------------------------------------------------
// Device-global scratch, 304 MB (proven loadable in R11/R12). Layouts:
//   g_bufA after k_fft1c  : [ca][ym(256)][kx(512)]  (ym = padded y - 128)
//   g_bufB after k_transA : [ca][kx(512)][ym(256)]
//   g_bufC after k_colfft : [ca][kx(512)][ky(512)]  (F spectra)
//   g_bufC after k_mix    : same slots, G = sum_ain K*F (in-place, pointwise)
//   g_bufA after k_colifft: [ca][kx(512)][ym(256)]  (ym = result y - 128)
//   g_bufB after k_transB : [ca][ym(256)][kx(512)]
//   g_bufA after k_outifft: [ca][h(256)][w(256)]
// ca = coil*A_ + a.
// ---------------------------------------------------------------------------
__device__ float2 g_bufA[RPG * 256 * 512];  //  63 MB
__device__ float2 g_bufB[RPG * 512 * 256];  //  63 MB
__device__ float2 g_bufC[RPG * 512 * 512];  // 126 MB
__device__ float2 g_kernT[25 * 512 * 512];  // 52.4 MB, transposed + pre-scaled

// ---------------------------------------------------------------------------
// LDS FFT with SoA floats + index padding (kills the float2 even-bank 4-way
// conflicts measured at 6.5M/dispatch in R12) and radix-4 stages (9 -> 5
// barriers / LDS round trips).
// ---------------------------------------------------------------------------
#define NP 528                      // 512 + 512/32 padding slots
__device__ inline int PADI(int i) { return i + (i >> 5); }

// tab[k] = e^{-2 pi i k/512}, k in [0,512) (radix-4 needs 3*e1 up to 378).
__device__ inline void build_tab512(float2* tab, int t) {
    #pragma unroll
    for (int q = 0; q < 4; ++q) {
        int k = t + q * 128;
        float s, c;
        __sincosf(-2.0f * PI_F * (float)k * (1.0f / 512.0f), &s, &c);
        tab[k] = make_float2(c, s);
    }
}

template<int DIR>
__device__ inline float2 cmulw(float2 v, float2 w) {
    float cv = w.x, sv = (DIR < 0) ? w.y : -w.y;   // DIR=+1 -> conj(w)
    return make_float2(v.x * cv - v.y * sv, v.x * sv + v.y * cv);
}

// 512-pt FFT: 4 radix-4 stages + 1 radix-2 stage, 128 threads.
// Input in (reA,imA) at PADI(i); on return sre/sim point to the result.
// Verified by hand at N=4/8/16 (delta inputs, twiddled and untwiddled paths).
template<int DIR>
__device__ void fft512_r4(float*& sre, float*& sim, float* dre, float* dim,
                          const float2* tab, int t) {
    float *srcR = sre, *srcI = sim, *dstR = dre, *dstI = dim;
    int Ns = 1;
    #pragma unroll
    for (int s = 0; s < 4; ++s) {
        __syncthreads();
        int j = t;                   // 0..127, one radix-4 butterfly each
        int m = j & (Ns - 1);
        int e1 = m << (7 - 2 * s);   // m*512/(4*Ns); 3*e1 < 512 for all stages
        float2 w1 = tab[e1], w2 = tab[2 * e1], w3 = tab[3 * e1];
        int i0 = PADI(j), i1 = PADI(j + 128), i2 = PADI(j + 256), i3 = PADI(j + 384);
        float2 v0 = make_float2(srcR[i0], srcI[i0]);
        float2 v1 = cmulw<DIR>(make_float2(srcR[i1], srcI[i1]), w1);
        float2 v2 = cmulw<DIR>(make_float2(srcR[i2], srcI[i2]), w2);
        float2 v3 = cmulw<DIR>(make_float2(srcR[i3], srcI[i3]), w3);
        float2 t0 = make_float2(v0.x + v2.x, v0.y + v2.y);
        float2 t1 = make_float2(v0.x - v2.x, v0.y - v2.y);
        float2 t2 = make_float2(v1.x + v3.x, v1.y + v3.y);
        float2 t3 = make_float2(v1.x - v3.x, v1.y - v3.y);
        float2 y0 = make_float2(t0.x + t2.x, t0.y + t2.y);
        float2 y2 = make_float2(t0.x - t2.x, t0.y - t2.y);
        float2 y1, y3;
        if (DIR < 0) {               // forward: y1 = t1 - i*t3, y3 = t1 + i*t3
            y1 = make_float2(t1.x + t3.y, t1.y - t3.x);
            y3 = make_float2(t1.x - t3.y, t1.y + t3.x);
        } else {                     // inverse: swapped
            y1 = make_float2(t1.x - t3.y, t1.y + t3.x);
            y3 = make_float2(t1.x + t3.y, t1.y - t3.x);
        }
        int idxD = ((j & ~(Ns - 1)) << 2) | m;
        int o0 = PADI(idxD), o1 = PADI(idxD + Ns);
        int o2 = PADI(idxD + 2 * Ns), o3 = PADI(idxD + 3 * Ns);
        dstR[o0] = y0.x; dstI[o0] = y0.y;
        dstR[o1] = y1.x; dstI[o1] = y1.y;
        dstR[o2] = y2.x; dstI[o2] = y2.y;
        dstR[o3] = y3.x; dstI[o3] = y3.y;
        float* tr = srcR; srcR = dstR; dstR = tr;
        float* ti = srcI; srcI = dstI; dstI = ti;
        Ns <<= 2;
    }
    // final radix-2 stage, Ns=256: m=j, e=m, idxD=j -> natural order
    __syncthreads();
    #pragma unroll
    for (int q = 0; q < 2; ++q) {
        int j = t + q * 128;         // 0..255
        float2 w = tab[j];
        int i0 = PADI(j), i1 = PADI(j + 256);
        float2 v0 = make_float2(srcR[i0], srcI[i0]);
        float2 tw = cmulw<DIR>(make_float2(srcR[i1], srcI[i1]), w);
        dstR[i0] = v0.x + tw.x; dstI[i0] = v0.y + tw.y;
        dstR[i1] = v0.x - tw.x; dstI[i1] = v0.y - tw.y;
    }
    __syncthreads();
    sre = dstR; sim = dstI;
}

// ---------------------------------------------------------------------------
// Transposed, pre-scaled kernel cache (SoA tile: float2 tiles alias even
// banks only -> 4-way conflicts; split re/im covers all 32 banks):
// g_kernT[m][kx*512+ky] = scale * kern[m][ky*512+kx], m = aout*5+ain.
// ---------------------------------------------------------------------------
__global__ void k_kernT2(const float* __restrict__ kr, const float* __restrict__ ki,
                         float scale) {
    __shared__ float tR[32][33], tI[32][33];
    int m = blockIdx.z;
    size_t base = (size_t)m << 18;
    int c0 = blockIdx.x * 32;
    int r0 = blockIdx.y * 32;
    int tx = threadIdx.x, ty = threadIdx.y;
    for (int i = ty; i < 32; i += 8) {
        size_t idx = base + (size_t)(c0 + i) * 512 + (r0 + tx);
        tR[i][tx] = kr[idx] * scale;
        tI[i][tx] = ki[idx] * scale;
    }
    __syncthreads();
    for (int i = ty; i < 32; i += 8)
        g_kernT[base + (size_t)(r0 + i) * 512 + (c0 + tx)] =
            make_float2(tR[tx][i], tI[tx][i]);
}

// ---------------------------------------------------------------------------
// Pad x + modulate mps_c*x + row FFT along x, banded store. Block = ca*256+ym.
// ---------------------------------------------------------------------------
__global__ void k_fft1c(const float* __restrict__ xr, const float* __restrict__ xi,
                        const float* __restrict__ mr, const float* __restrict__ mi) {
    int row = blockIdx.x;            // ca*256 + ym
    int ca = row >> 8;
    int ym = row & 255;
    int coil = ca / A_;
    int a = ca - coil * A_;
    int t = threadIdx.x;
    __shared__ float reA[NP], imA[NP], reB[NP], imB[NP];
    __shared__ float2 tab[512];
    build_tab512(tab, t);
    size_t xBase = ((size_t)a * 256 + ym) * 256;
    size_t mBase = ((size_t)coil * 256 + ym) * 256;
    #pragma unroll
    for (int q = 0; q < 4; ++q) {
        int x5 = t + q * 128;
        float vr = 0.f, vi = 0.f;
        if (x5 >= 128 && x5 < 384) {
            int xm = x5 - 128;
            float ar = xr[xBase + xm], ai = xi[xBase + xm];
            float br = mr[mBase + xm], bi = mi[mBase + xm];
            vr = ar * br - ai * bi;
            vi = ar * bi + ai * br;
        }
        int p = PADI(x5);
        reA[p] = vr; imA[p] = vi;
    }
    float *sre = reA, *sim = imA;
    fft512_r4<-1>(sre, sim, reB, imB, tab, t);
    float2* o = g_bufA + (size_t)row * 512;
    #pragma unroll
    for (int q = 0; q < 4; ++q) {
        int k = t + q * 128;
        int p = PADI(k);
        o[k] = make_float2(sre[p], sim[p]);
    }
}

// ---------------------------------------------------------------------------
// transA: per-ca transpose (256 ym x 512 kx) -> (512 kx x 256 ym). SoA tile.
// ---------------------------------------------------------------------------
__global__ void k_transA() {
    __shared__ float tR[32][33], tI[32][33];
    int ca = blockIdx.z;
    const float2* sIn = g_bufA + (size_t)ca * (256 * 512);
    float2* sOut = g_bufB + (size_t)ca * (512 * 256);
    int kx0 = blockIdx.x * 32, ym0 = blockIdx.y * 32;
    int tx = threadIdx.x, ty = threadIdx.y;
    for (int i = ty; i < 32; i += 8) {
        float2 v = sIn[(size_t)(ym0 + i) * 512 + kx0 + tx];
        tR[i][tx] = v.x; tI[i][tx] = v.y;
    }
    __syncthreads();
    for (int i = ty; i < 32; i += 8)
        sOut[(size_t)(kx0 + i) * 256 + ym0 + tx] =
            make_float2(tR[tx][i], tI[tx][i]);
}

// ---------------------------------------------------------------------------
// Column FFT with pad-on-load: block = ca*512 + kx.
// ---------------------------------------------------------------------------
__global__ void k_colfft() {
    int blk = blockIdx.x;            // ca*512 + kx
    int t = threadIdx.x;
    __shared__ float reA[NP], imA[NP], reB[NP], imB[NP];
    __shared__ float2 tab[512];
    build_tab512(tab, t);
    const float2* grow = g_bufB + (size_t)blk * 256;
    #pragma unroll
    for (int q = 0; q < 4; ++q) {
        int y = t + q * 128;
        float2 v = (y >= 128 && y < 384) ? grow[y - 128] : make_float2(0.f, 0.f);
        int p = PADI(y);
        reA[p] = v.x; imA[p] = v.y;
    }
    float *sre = reA, *sim = imA;
    fft512_r4<-1>(sre, sim, reB, imB, tab, t);
    float2* o = g_bufC + (size_t)blk * 512;
    #pragma unroll
    for (int q = 0; q < 4; ++q) {
        int k = t + q * 128;
        int p = PADI(k);
        o[k] = make_float2(sre[p], sim[p]);
    }
}

// ---------------------------------------------------------------------------
// Pointwise k-space mix, IN PLACE over bufC (R12-proven): each thread owns
// one (kx,ky), 25 kernT values in registers, loops 12 coils.
// ---------------------------------------------------------------------------
__global__ void __launch_bounds__(256) k_mix() {
    int blk = blockIdx.x;                    // kx*2 + half
    int kx = blk >> 1;
    int ky = ((blk & 1) << 8) + threadIdx.x; // 0..511
    size_t off = ((size_t)kx << 9) + ky;
    float2 K[25];
    #pragma unroll
    for (int m = 0; m < 25; ++m)
        K[m] = g_kernT[((size_t)m << 18) + off];
    for (int cl = 0; cl < C_; ++cl) {
        float2 F[A_], G[A_];
        #pragma unroll
        for (int ain = 0; ain < A_; ++ain)
            F[ain] = g_bufC[((size_t)(cl * A_ + ain) << 18) + off];
        #pragma unroll
        for (int aout = 0; aout < A_; ++aout) {
            float2 acc = make_float2(0.f, 0.f);
            #pragma unroll
            for (int ain = 0; ain < A_; ++ain) {
                float2 k = K[aout * A_ + ain];
                acc.x += k.x * F[ain].x - k.y * F[ain].y;
                acc.y += k.x * F[ain].y + k.y * F[ain].x;
            }
            G[aout] = acc;
        }
        #pragma unroll
        for (int aout = 0; aout < A_; ++aout)
            g_bufC[((size_t)(cl * A_ + aout) << 18) + off] = G[aout];
    }
}

// ---------------------------------------------------------------------------
// Column IFFT over ky, banded store of the surviving center band.
// ---------------------------------------------------------------------------
__global__ void k_colifft() {
    int blk = blockIdx.x;            // ca*512 + kx
    int t = threadIdx.x;
    __shared__ float reA[NP], imA[NP], reB[NP], imB[NP];
    __shared__ float2 tab[512];
    build_tab512(tab, t);
    const float2* g = g_bufC + (size_t)blk * 512;
    #pragma unroll
    for (int q = 0; q < 4; ++q) {
        int k = t + q * 128;
        float2 v = g[k];
        int p = PADI(k);
        reA[p] = v.x; imA[p] = v.y;
    }
    float *sre = reA, *sim = imA;
    fft512_r4<1>(sre, sim, reB, imB, tab, t);
    // keep y in [128,384) -> ym = y-128; store [ca][kx][ym]
    float2* o = g_bufA + (size_t)blk * 256;
    int p0 = PADI(t + 128), p1 = PADI(t + 256);
    o[t]       = make_float2(sre[p0], sim[p0]);
    o[t + 128] = make_float2(sre[p1], sim[p1]);
}

// ---------------------------------------------------------------------------
// transB: per-ca transpose (512 kx x 256 ym) -> (256 ym x 512 kx). SoA tile.
// ---------------------------------------------------------------------------
__global__ void k_transB() {
    __shared__ float tR[32][33], tI[32][33];
    int ca = blockIdx.z;
    const float2* sIn = g_bufA + (size_t)ca * (512 * 256);
    float2* sOut = g_bufB + (size_t)ca * (256 * 512);
    int ym0 = blockIdx.x * 32, kx0 = blockIdx.y * 32;
    int tx = threadIdx.x, ty = threadIdx.y;
    for (int i = ty; i < 32; i += 8) {
        float2 v = sIn[(size_t)(kx0 + i) * 256 + ym0 + tx];
        tR[i][tx] = v.x; tI[i][tx] = v.y;
    }
    __syncthreads();
    for (int i = ty; i < 32; i += 8)
        sOut[(size_t)(ym0 + i) * 512 + kx0 + tx] =
            make_float2(tR[tx][i], tI[tx][i]);
}

// ---------------------------------------------------------------------------
// Row IFFT along kx + crop x, banded store [ca][h][w(256)].
// ---------------------------------------------------------------------------
__global__ void k_outifft() {
    int row = blockIdx.x;            // ca*256 + h
    int t = threadIdx.x;
    __shared__ float reA[NP], imA[NP], reB[NP], imB[NP];
    __shared__ float2 tab[512];
    build_tab512(tab, t);
    const float2* s = g_bufB + (size_t)row * 512;
    #pragma unroll
    for (int q = 0; q < 4; ++q) {
        int k = t + q * 128;
        float2 v = s[k];
        int p = PADI(k);
        reA[p] = v.x; imA[p] = v.y;
    }
    float *sre = reA, *sim = imA;
    fft512_r4<1>(sre, sim, reB, imB, tab, t);
    float2* o = g_bufA + (size_t)row * 256;
    #pragma unroll
    for (int q = 0; q < 2; ++q) {
        int w = t + q * 128;
        int p = PADI(w + 128);       // crop x: keep [128,384)
        o[w] = make_float2(sre[p], sim[p]);
    }
}

// ---------------------------------------------------------------------------
// Coil reduction: out[a,h,w] = sum_c conj(mps[c,h,w]) * v[c,a,h,w].
// Planar out: Re plane [5,256,256] then Im plane. Plain writes only.
// ---------------------------------------------------------------------------
__global__ void k_outred(const float* __restrict__ mr, const float* __restrict__ mi,
                         float* __restrict__ out, int outFloats) {
    int row = blockIdx.x;            // a*256 + h
    int a = row >> 8;
    int h = row & 255;
    int w = threadIdx.x;             // 0..255
    float ar = 0.f, ai = 0.f;
    #pragma unroll
    for (int c = 0; c < C_; ++c) {
        float2 v = g_bufA[(((size_t)(c * A_ + a) * 256 + h)) * 256 + w];
        size_t mIdx = ((size_t)c * 256 + h) * 256 + w;
        float br = mr[mIdx], bi = -mi[mIdx];   // conj(mps)
        ar += v.x * br - v.y * bi;
        ai += v.x * bi + v.y * br;
    }
    size_t p = ((size_t)a * 256 + h) * 256 + w;
    size_t reIdx = p, imIdx = 327680 + p;
    if (reIdx < (size_t)outFloats) out[reIdx] = ar;
    if (imIdx < (size_t)outFloats) out[imIdx] = ai;
}

// ---------------------------------------------------------------------------
extern "C" void kernel_launch(void* const* d_in, const int* in_sizes, int n_in,
                              void* d_out, int out_size, void* d_ws, size_t ws_size,
                              hipStream_t stream) {
    const float* xr = (const float*)d_in[0];
    const float* xi = (const float*)d_in[1];
    const float* mr = (const float*)d_in[2];
    const float* mi = (const float*)d_in[3];
    const float* kr = (const float*)d_in[4];
    const float* ki = (const float*)d_in[5];
    float* out = (float*)d_out;
    (void)d_ws; (void)ws_size; (void)n_in; (void)in_sizes;

    const float scale = 4.0f / 262144.0f;   // OVERSAMP^2/(Hp*Wp), ortho norms

    k_kernT2 <<<dim3(16, 16, 25), dim3(32, 8), 0, stream>>>(kr, ki, scale);
    k_fft1c  <<<RPG * 256, 128, 0, stream>>>(xr, xi, mr, mi);
    k_transA <<<dim3(16, 8, RPG), dim3(32, 8), 0, stream>>>();
    k_colfft <<<RPG * 512, 128, 0, stream>>>();
    k_mix    <<<1024, 256, 0, stream>>>();
    k_colifft<<<RPG * 512, 128, 0, stream>>>();
    k_transB <<<dim3(8, 16, RPG), dim3(32, 8), 0, stream>>>();
    k_outifft<<<RPG * 256, 128, 0, stream>>>();
    k_outred <<<A_ * 256, 256, 0, stream>>>(mr, mi, out, out_size);
}

// Round 14
// 385.112 us; speedup vs baseline: 1.1726x; 1.0116x over previous
//
#include <hip/hip_runtime.h>
#include <cstddef>

#define PI_F 3.14159265358979323846f
#define A_  5
#define C_  12
#define RPG (C_ * A_)    // (coil,a) rows = 60

// ---------------------------------------------------------------------------
// Device-global scratch, 304 MB (proven loadable R11-R13). Layouts:
//   g_bufA after k_fft1c  : [ca][ym(256)][kx(512)]  (ym = padded y - 128)
//   g_bufB after k_transA : [ca][kx(512)][ym(256)]
//   g_bufC after k_colfft : [ca][kx(512)][ky(512)]  (F spectra)
//   g_bufC after k_mix    : same slots, G = sum_ain K*F (in-place, pointwise)
//   g_bufA after k_colifft: [ca][kx(512)][ym(256)]  (ym = result y - 128)
//   g_bufB after k_transB : [ca][ym(256)][kx(512)]
//   g_bufA after k_outifft: [ca][h(256)][w(256)]
// ca = coil*A_ + a.
// ---------------------------------------------------------------------------
__device__ float2 g_bufA[RPG * 256 * 512];  //  63 MB
__device__ float2 g_bufB[RPG * 512 * 256];  //  63 MB
__device__ float2 g_bufC[RPG * 512 * 512];  // 126 MB
__device__ float2 g_kernT[25 * 512 * 512];  // 52.4 MB, transposed + pre-scaled

// ---------------------------------------------------------------------------
// SoA LDS FFT, index padding, radix-4 (R13-proven: bank conflicts 6.5M -> 0).
// ---------------------------------------------------------------------------
#define NP 528
__device__ inline int PADI(int i) { return i + (i >> 5); }

__device__ inline void build_tab512(float2* tab, int t) {
    #pragma unroll
    for (int q = 0; q < 4; ++q) {
        int k = t + q * 128;
        float s, c;
        __sincosf(-2.0f * PI_F * (float)k * (1.0f / 512.0f), &s, &c);
        tab[k] = make_float2(c, s);
    }
}

template<int DIR>
__device__ inline float2 cmulw(float2 v, float2 w) {
    float cv = w.x, sv = (DIR < 0) ? w.y : -w.y;   // DIR=+1 -> conj(w)
    return make_float2(v.x * cv - v.y * sv, v.x * sv + v.y * cv);
}

// 512-pt FFT: 4 radix-4 stages + 1 radix-2 stage, 128 threads.
template<int DIR>
__device__ void fft512_r4(float*& sre, float*& sim, float* dre, float* dim,
                          const float2* tab, int t) {
    float *srcR = sre, *srcI = sim, *dstR = dre, *dstI = dim;
    int Ns = 1;
    #pragma unroll
    for (int s = 0; s < 4; ++s) {
        __syncthreads();
        int j = t;
        int m = j & (Ns - 1);
        int e1 = m << (7 - 2 * s);
        float2 w1 = tab[e1], w2 = tab[2 * e1], w3 = tab[3 * e1];
        int i0 = PADI(j), i1 = PADI(j + 128), i2 = PADI(j + 256), i3 = PADI(j + 384);
        float2 v0 = make_float2(srcR[i0], srcI[i0]);
        float2 v1 = cmulw<DIR>(make_float2(srcR[i1], srcI[i1]), w1);
        float2 v2 = cmulw<DIR>(make_float2(srcR[i2], srcI[i2]), w2);
        float2 v3 = cmulw<DIR>(make_float2(srcR[i3], srcI[i3]), w3);
        float2 t0 = make_float2(v0.x + v2.x, v0.y + v2.y);
        float2 t1 = make_float2(v0.x - v2.x, v0.y - v2.y);
        float2 t2 = make_float2(v1.x + v3.x, v1.y + v3.y);
        float2 t3 = make_float2(v1.x - v3.x, v1.y - v3.y);
        float2 y0 = make_float2(t0.x + t2.x, t0.y + t2.y);
        float2 y2 = make_float2(t0.x - t2.x, t0.y - t2.y);
        float2 y1, y3;
        if (DIR < 0) {
            y1 = make_float2(t1.x + t3.y, t1.y - t3.x);
            y3 = make_float2(t1.x - t3.y, t1.y + t3.x);
        } else {
            y1 = make_float2(t1.x - t3.y, t1.y + t3.x);
            y3 = make_float2(t1.x + t3.y, t1.y - t3.x);
        }
        int idxD = ((j & ~(Ns - 1)) << 2) | m;
        int o0 = PADI(idxD), o1 = PADI(idxD + Ns);
        int o2 = PADI(idxD + 2 * Ns), o3 = PADI(idxD + 3 * Ns);
        dstR[o0] = y0.x; dstI[o0] = y0.y;
        dstR[o1] = y1.x; dstI[o1] = y1.y;
        dstR[o2] = y2.x; dstI[o2] = y2.y;
        dstR[o3] = y3.x; dstI[o3] = y3.y;
        float* tr = srcR; srcR = dstR; dstR = tr;
        float* ti = srcI; srcI = dstI; dstI = ti;
        Ns <<= 2;
    }
    __syncthreads();
    #pragma unroll
    for (int q = 0; q < 2; ++q) {
        int j = t + q * 128;
        float2 w = tab[j];
        int i0 = PADI(j), i1 = PADI(j + 256);
        float2 v0 = make_float2(srcR[i0], srcI[i0]);
        float2 tw = cmulw<DIR>(make_float2(srcR[i1], srcI[i1]), w);
        dstR[i0] = v0.x + tw.x; dstI[i0] = v0.y + tw.y;
        dstR[i1] = v0.x - tw.x; dstI[i1] = v0.y - tw.y;
    }
    __syncthreads();
    sre = dstR; sim = dstI;
}

// ---------------------------------------------------------------------------
// Transposed, pre-scaled kernel cache (SoA tiles).
// ---------------------------------------------------------------------------
__global__ void k_kernT2(const float* __restrict__ kr, const float* __restrict__ ki,
                         float scale) {
    __shared__ float tR[32][33], tI[32][33];
    int m = blockIdx.z;
    size_t base = (size_t)m << 18;
    int c0 = blockIdx.x * 32;
    int r0 = blockIdx.y * 32;
    int tx = threadIdx.x, ty = threadIdx.y;
    for (int i = ty; i < 32; i += 8) {
        size_t idx = base + (size_t)(c0 + i) * 512 + (r0 + tx);
        tR[i][tx] = kr[idx] * scale;
        tI[i][tx] = ki[idx] * scale;
    }
    __syncthreads();
    for (int i = ty; i < 32; i += 8)
        g_kernT[base + (size_t)(r0 + i) * 512 + (c0 + tx)] =
            make_float2(tR[tx][i], tI[tx][i]);
}

// ---------------------------------------------------------------------------
// Pad x + modulate mps_c*x + row FFT along x, banded store. Block = ca*256+ym.
// ---------------------------------------------------------------------------
__global__ void k_fft1c(const float* __restrict__ xr, const float* __restrict__ xi,
                        const float* __restrict__ mr, const float* __restrict__ mi) {
    int row = blockIdx.x;
    int ca = row >> 8;
    int ym = row & 255;
    int coil = ca / A_;
    int a = ca - coil * A_;
    int t = threadIdx.x;
    __shared__ float reA[NP], imA[NP], reB[NP], imB[NP];
    __shared__ float2 tab[512];
    build_tab512(tab, t);
    size_t xBase = ((size_t)a * 256 + ym) * 256;
    size_t mBase = ((size_t)coil * 256 + ym) * 256;
    #pragma unroll
    for (int q = 0; q < 4; ++q) {
        int x5 = t + q * 128;
        float vr = 0.f, vi = 0.f;
        if (x5 >= 128 && x5 < 384) {
            int xm = x5 - 128;
            float ar = xr[xBase + xm], ai = xi[xBase + xm];
            float br = mr[mBase + xm], bi = mi[mBase + xm];
            vr = ar * br - ai * bi;
            vi = ar * bi + ai * br;
        }
        int p = PADI(x5);
        reA[p] = vr; imA[p] = vi;
    }
    float *sre = reA, *sim = imA;
    fft512_r4<-1>(sre, sim, reB, imB, tab, t);
    float2* o = g_bufA + (size_t)row * 512;
    #pragma unroll
    for (int q = 0; q < 4; ++q) {
        int k = t + q * 128;
        int p = PADI(k);
        o[k] = make_float2(sre[p], sim[p]);
    }
}

// ---------------------------------------------------------------------------
// transA: per-ca transpose (256 ym x 512 kx) -> (512 kx x 256 ym). SoA tile.
// ---------------------------------------------------------------------------
__global__ void k_transA() {
    __shared__ float tR[32][33], tI[32][33];
    int ca = blockIdx.z;
    const float2* sIn = g_bufA + (size_t)ca * (256 * 512);
    float2* sOut = g_bufB + (size_t)ca * (512 * 256);
    int kx0 = blockIdx.x * 32, ym0 = blockIdx.y * 32;
    int tx = threadIdx.x, ty = threadIdx.y;
    for (int i = ty; i < 32; i += 8) {
        float2 v = sIn[(size_t)(ym0 + i) * 512 + kx0 + tx];
        tR[i][tx] = v.x; tI[i][tx] = v.y;
    }
    __syncthreads();
    for (int i = ty; i < 32; i += 8)
        sOut[(size_t)(kx0 + i) * 256 + ym0 + tx] =
            make_float2(tR[tx][i], tI[tx][i]);
}

// ---------------------------------------------------------------------------
// Column FFT with pad-on-load, float4 (16 B/lane) global I/O.
// Block = ca*512 + kx.
// ---------------------------------------------------------------------------
__global__ void k_colfft() {
    int blk = blockIdx.x;            // ca*512 + kx
    int t = threadIdx.x;
    __shared__ float reA[NP], imA[NP], reB[NP], imB[NP];
    __shared__ float2 tab[512];
    build_tab512(tab, t);
    // banded input: 256 float2 = 128 float4; thread t loads one float4
    const float4* g4 = (const float4*)(g_bufB + (size_t)blk * 256);
    float4 v = g4[t];                // elements 2t, 2t+1 -> y = 128+2t, 129+2t
    {
        int y0 = 128 + 2 * t, y1 = y0 + 1;
        int p0 = PADI(y0), p1 = PADI(y1);
        reA[p0] = v.x; imA[p0] = v.y;
        reA[p1] = v.z; imA[p1] = v.w;
        // zero the pad regions: y in [0,128) U [384,512)
        int z0 = t;                  // 0..127
        int z1 = t + 384;            // 384..511
        int q0 = PADI(z0), q1 = PADI(z1);
        reA[q0] = 0.f; imA[q0] = 0.f;
        reA[q1] = 0.f; imA[q1] = 0.f;
    }
    float *sre = reA, *sim = imA;
    fft512_r4<-1>(sre, sim, reB, imB, tab, t);
    float4* o4 = (float4*)(g_bufC + (size_t)blk * 512);
    #pragma unroll
    for (int q = 0; q < 2; ++q) {
        int e = t + q * 128;         // float4 index 0..255 -> elements 2e,2e+1
        int p0 = PADI(2 * e), p1 = PADI(2 * e + 1);
        o4[e] = make_float4(sre[p0], sim[p0], sre[p1], sim[p1]);
    }
}

// ---------------------------------------------------------------------------
// Pointwise k-space mix, in place over bufC, SOFTWARE-PIPELINED: prefetch
// coil c+1's F during coil c's compute+store (R13 showed VALUBusy 15%,
// hbm 44%, occupancy grid-limited at 4 waves/SIMD -> latency-bound; doubling
// outstanding loads is the lever). Per-thread k-point ownership unchanged ->
// in-place remains race-free; prefetch addresses disjoint from stores.
// ---------------------------------------------------------------------------
__global__ void __launch_bounds__(256) k_mix() {
    int blk = blockIdx.x;                    // kx*2 + half
    int kx = blk >> 1;
    int ky = ((blk & 1) << 8) + threadIdx.x;
    size_t off = ((size_t)kx << 9) + ky;
    float2 K[25];
    #pragma unroll
    for (int m = 0; m < 25; ++m)
        K[m] = g_kernT[((size_t)m << 18) + off];
    float2 F[A_], Fn[A_];
    #pragma unroll
    for (int ain = 0; ain < A_; ++ain)
        F[ain] = g_bufC[((size_t)ain << 18) + off];
    for (int cl = 0; cl < C_; ++cl) {
        if (cl + 1 < C_) {
            #pragma unroll
            for (int ain = 0; ain < A_; ++ain)
                Fn[ain] = g_bufC[((size_t)((cl + 1) * A_ + ain) << 18) + off];
        }
        #pragma unroll
        for (int aout = 0; aout < A_; ++aout) {
            float2 acc = make_float2(0.f, 0.f);
            #pragma unroll
            for (int ain = 0; ain < A_; ++ain) {
                float2 k = K[aout * A_ + ain];
                acc.x += k.x * F[ain].x - k.y * F[ain].y;
                acc.y += k.x * F[ain].y + k.y * F[ain].x;
            }
            g_bufC[((size_t)(cl * A_ + aout) << 18) + off] = acc;
        }
        #pragma unroll
        for (int ain = 0; ain < A_; ++ain) F[ain] = Fn[ain];
    }
}

// ---------------------------------------------------------------------------
// Column IFFT over ky, float4 input, banded float4 store.
// ---------------------------------------------------------------------------
__global__ void k_colifft() {
    int blk = blockIdx.x;            // ca*512 + kx
    int t = threadIdx.x;
    __shared__ float reA[NP], imA[NP], reB[NP], imB[NP];
    __shared__ float2 tab[512];
    build_tab512(tab, t);
    const float4* g4 = (const float4*)(g_bufC + (size_t)blk * 512);
    #pragma unroll
    for (int q = 0; q < 2; ++q) {
        int e = t + q * 128;         // float4 index -> elements 2e, 2e+1
        float4 v = g4[e];
        int p0 = PADI(2 * e), p1 = PADI(2 * e + 1);
        reA[p0] = v.x; imA[p0] = v.y;
        reA[p1] = v.z; imA[p1] = v.w;
    }
    float *sre = reA, *sim = imA;
    fft512_r4<1>(sre, sim, reB, imB, tab, t);
    // keep y in [128,384): 256 float2 = 128 float4; thread t stores one
    float4* o4 = (float4*)(g_bufA + (size_t)blk * 256);
    int y0 = 128 + 2 * t;
    int p0 = PADI(y0), p1 = PADI(y0 + 1);
    o4[t] = make_float4(sre[p0], sim[p0], sre[p1], sim[p1]);
}

// ---------------------------------------------------------------------------
// transB: per-ca transpose (512 kx x 256 ym) -> (256 ym x 512 kx). SoA tile.
// ---------------------------------------------------------------------------
__global__ void k_transB() {
    __shared__ float tR[32][33], tI[32][33];
    int ca = blockIdx.z;
    const float2* sIn = g_bufA + (size_t)ca * (512 * 256);
    float2* sOut = g_bufB + (size_t)ca * (256 * 512);
    int ym0 = blockIdx.x * 32, kx0 = blockIdx.y * 32;
    int tx = threadIdx.x, ty = threadIdx.y;
    for (int i = ty; i < 32; i += 8) {
        float2 v = sIn[(size_t)(kx0 + i) * 256 + ym0 + tx];
        tR[i][tx] = v.x; tI[i][tx] = v.y;
    }
    __syncthreads();
    for (int i = ty; i < 32; i += 8)
        sOut[(size_t)(ym0 + i) * 512 + kx0 + tx] =
            make_float2(tR[tx][i], tI[tx][i]);
}

// ---------------------------------------------------------------------------
// Row IFFT along kx + crop x, float4 input, banded store [ca][h][w(256)].
// ---------------------------------------------------------------------------
__global__ void k_outifft() {
    int row = blockIdx.x;            // ca*256 + h
    int t = threadIdx.x;
    __shared__ float reA[NP], imA[NP], reB[NP], imB[NP];
    __shared__ float2 tab[512];
    build_tab512(tab, t);
    const float4* s4 = (const float4*)(g_bufB + (size_t)row * 512);
    #pragma unroll
    for (int q = 0; q < 2; ++q) {
        int e = t + q * 128;
        float4 v = s4[e];
        int p0 = PADI(2 * e), p1 = PADI(2 * e + 1);
        reA[p0] = v.x; imA[p0] = v.y;
        reA[p1] = v.z; imA[p1] = v.w;
    }
    float *sre = reA, *sim = imA;
    fft512_r4<1>(sre, sim, reB, imB, tab, t);
    float4* o4 = (float4*)(g_bufA + (size_t)row * 256);
    int w0 = 128 + 2 * t;            // crop x: keep [128,384)
    int p0 = PADI(w0), p1 = PADI(w0 + 1);
    o4[t] = make_float4(sre[p0], sim[p0], sre[p1], sim[p1]);
}

// ---------------------------------------------------------------------------
// Coil reduction: out[a,h,w] = sum_c conj(mps[c,h,w]) * v[c,a,h,w].
// Planar out: Re plane [5,256,256] then Im plane. Plain writes only.
// ---------------------------------------------------------------------------
__global__ void k_outred(const float* __restrict__ mr, const float* __restrict__ mi,
                         float* __restrict__ out, int outFloats) {
    int row = blockIdx.x;            // a*256 + h
    int a = row >> 8;
    int h = row & 255;
    int w = threadIdx.x;             // 0..255
    float ar = 0.f, ai = 0.f;
    #pragma unroll
    for (int c = 0; c < C_; ++c) {
        float2 v = g_bufA[(((size_t)(c * A_ + a) * 256 + h)) * 256 + w];
        size_t mIdx = ((size_t)c * 256 + h) * 256 + w;
        float br = mr[mIdx], bi = -mi[mIdx];   // conj(mps)
        ar += v.x * br - v.y * bi;
        ai += v.x * bi + v.y * br;
    }
    size_t p = ((size_t)a * 256 + h) * 256 + w;
    size_t reIdx = p, imIdx = 327680 + p;
    if (reIdx < (size_t)outFloats) out[reIdx] = ar;
    if (imIdx < (size_t)outFloats) out[imIdx] = ai;
}

// ---------------------------------------------------------------------------
extern "C" void kernel_launch(void* const* d_in, const int* in_sizes, int n_in,
                              void* d_out, int out_size, void* d_ws, size_t ws_size,
                              hipStream_t stream) {
    const float* xr = (const float*)d_in[0];
    const float* xi = (const float*)d_in[1];
    const float* mr = (const float*)d_in[2];
    const float* mi = (const float*)d_in[3];
    const float* kr = (const float*)d_in[4];
    const float* ki = (const float*)d_in[5];
    float* out = (float*)d_out;
    (void)d_ws; (void)ws_size; (void)n_in; (void)in_sizes;

    const float scale = 4.0f / 262144.0f;   // OVERSAMP^2/(Hp*Wp), ortho norms

    k_kernT2 <<<dim3(16, 16, 25), dim3(32, 8), 0, stream>>>(kr, ki, scale);
    k_fft1c  <<<RPG * 256, 128, 0, stream>>>(xr, xi, mr, mi);
    k_transA <<<dim3(16, 8, RPG), dim3(32, 8), 0, stream>>>();
    k_colfft <<<RPG * 512, 128, 0, stream>>>();
    k_mix    <<<1024, 256, 0, stream>>>();
    k_colifft<<<RPG * 512, 128, 0, stream>>>();
    k_transB <<<dim3(8, 16, RPG), dim3(32, 8), 0, stream>>>();
    k_outifft<<<RPG * 256, 128, 0, stream>>>();
    k_outred <<<A_ * 256, 256, 0, stream>>>(mr, mi, out, out_size);
}